// Round 1
// baseline (6548.664 us; speedup 1.0000x reference)
//
#include <hip/hip_runtime.h>
#include <stdint.h>

// TopoSignature: two Prim MSTs over dense 4096x4096 distance matrices + edge
// signature cross-comparison. Latency-bound sequential algorithm: one block
// per MST (2 blocks total), 256 threads, min_dist/parent in registers.

#define N      4096
#define NT     256        // threads per block
#define EPT    16         // elements (columns) per thread
#define NEDGE  (N - 1)

__device__ __forceinline__ uint32_t fbits(float f) { return __float_as_uint(f); }

__launch_bounds__(NT, 1)
__global__ void mst_kernel(const float* __restrict__ d1,
                           const float* __restrict__ d2,
                           float* __restrict__ out)
{
    const int b = blockIdx.x;                 // 0: MST of d1, 1: MST of d2
    const float* __restrict__ own   = (b == 0) ? d1 : d2;
    const float* __restrict__ other = (b == 0) ? d2 : d1;

    const int tid  = threadIdx.x;
    const int lane = tid & 63;
    const int wave = tid >> 6;

    // [parity][wave][{tkey, e, parent, pad}] — parity double-buffer so one
    // barrier per iteration suffices.
    __shared__ uint32_t cand[2][4][4];
    __shared__ uint32_t edges[NEDGE];         // (parent<<12)|j per Prim step
    __shared__ float    part[4];

    // Thread-local state. Element index for slot s (s = c*4+q):
    //   e = c*1024 + tid*4 + q   (bits: c in 11:10, tid*4 in 9:2, q in 1:0)
    float    md[EPT];
    uint32_t par[EPT];
    const uint32_t tid4 = (uint32_t)tid << 2;

    // ---- init: min_dist = d[0], parent = 0. md[e=0] = d[0][0] = 0.0 which
    // is the "in tree" marker (auto-excluded by the bits-1 transform). ----
    {
        const float4* r0 = (const float4*)own;   // row 0
        #pragma unroll
        for (int c = 0; c < 4; ++c) {
            float4 v = r0[c * 256 + tid];
            md[c*4+0] = v.x; md[c*4+1] = v.y; md[c*4+2] = v.z; md[c*4+3] = v.w;
            par[c*4+0] = 0u; par[c*4+1] = 0u; par[c*4+2] = 0u; par[c*4+3] = 0u;
        }
    }

    for (int it = 0; it < NEDGE; ++it) {
        // ---- local argmin over 16 slots ----
        // transform: t = float_bits(md) - 1 (unsigned). Positive floats keep
        // their order; md == 0.0 (in-tree) wraps to 0xFFFFFFFF (excluded).
        // Slot iteration order == ascending element index, so strict '<'
        // keeps the first (lowest-index) occurrence, matching jnp.argmin.
        uint32_t bt = fbits(md[0]) - 1u;
        uint32_t bs = 0u;
        uint32_t bp = par[0];
        #pragma unroll
        for (int s = 1; s < EPT; ++s) {
            uint32_t t = fbits(md[s]) - 1u;
            if (t < bt) { bt = t; bs = (uint32_t)s; bp = par[s]; }
        }
        uint32_t be = ((bs >> 2) << 10) | tid4 | (bs & 3u);

        // ---- wave argmin (explicit lowest-index tie-break) ----
        #pragma unroll
        for (int off = 32; off >= 1; off >>= 1) {
            uint32_t t2 = (uint32_t)__shfl_down((int)bt, off, 64);
            uint32_t e2 = (uint32_t)__shfl_down((int)be, off, 64);
            uint32_t p2 = (uint32_t)__shfl_down((int)bp, off, 64);
            if (t2 < bt || (t2 == bt && e2 < be)) { bt = t2; be = e2; bp = p2; }
        }
        if (lane == 0) {
            cand[it & 1][wave][0] = bt;
            cand[it & 1][wave][1] = be;
            cand[it & 1][wave][2] = bp;
        }
        __syncthreads();

        // ---- cross-wave argmin (redundant on all threads; no 2nd barrier) ----
        uint32_t wt = cand[it & 1][0][0];
        uint32_t we = cand[it & 1][0][1];
        uint32_t wp = cand[it & 1][0][2];
        #pragma unroll
        for (int w = 1; w < 4; ++w) {
            uint32_t t2 = cand[it & 1][w][0];
            uint32_t e2 = cand[it & 1][w][1];
            uint32_t p2 = cand[it & 1][w][2];
            if (t2 < wt || (t2 == wt && e2 < we)) { wt = t2; we = e2; wp = p2; }
        }
        if (tid == 0) edges[it] = (wp << 12) | we;

        // ---- load row `we` (coalesced float4) and relax ----
        const float4* r = (const float4*)(own + (size_t)we * N);
        float4 v0 = r[          tid];
        float4 v1 = r[256 +     tid];
        float4 v2 = r[512 +     tid];
        float4 v3 = r[768 +     tid];

        // Element e == we gets d[we][we] = 0.0 -> becomes the in-tree marker
        // automatically. In-tree elements (md == 0.0) can never be updated
        // since row values are > 0 off-diagonal (strict <).
        #pragma unroll
        for (int c = 0; c < 4; ++c) {
            float4 v = (c == 0) ? v0 : (c == 1) ? v1 : (c == 2) ? v2 : v3;
            float e0 = v.x, e1 = v.y, e2v = v.z, e3 = v.w;
            if (e0  < md[c*4+0]) { md[c*4+0] = e0;  par[c*4+0] = we; }
            if (e1  < md[c*4+1]) { md[c*4+1] = e1;  par[c*4+1] = we; }
            if (e2v < md[c*4+2]) { md[c*4+2] = e2v; par[c*4+2] = we; }
            if (e3  < md[c*4+3]) { md[c*4+3] = e3;  par[c*4+3] = we; }
        }
    }

    // ---- epilogue: gather both matrices at every MST edge, sum sq-diff ----
    __syncthreads();
    float acc = 0.0f;
    #pragma unroll
    for (int u = 0; u < EPT; ++u) {
        int i = u * NT + tid;
        if (i < NEDGE) {
            uint32_t pk = edges[i];
            uint32_t p  = pk >> 12;
            uint32_t e  = pk & 0xFFFu;
            size_t   off = (size_t)p * N + e;
            float a  = own[off];     // exact sig_own  = d_own[parent, j]
            float bb = other[off];   // exact sig_cross = d_other[parent, j]
            float df = a - bb;
            acc += df * df;
        }
    }
    #pragma unroll
    for (int off = 32; off >= 1; off >>= 1)
        acc += __shfl_down(acc, off, 64);
    if (lane == 0) part[wave] = acc;
    __syncthreads();
    if (tid == 0) {
        atomicAdd(out, part[0] + part[1] + part[2] + part[3]);
    }
}

extern "C" void kernel_launch(void* const* d_in, const int* in_sizes, int n_in,
                              void* d_out, int out_size, void* d_ws, size_t ws_size,
                              hipStream_t stream) {
    (void)in_sizes; (void)n_in; (void)out_size; (void)d_ws; (void)ws_size;
    const float* d1 = (const float*)d_in[0];
    const float* d2 = (const float*)d_in[1];
    float* out = (float*)d_out;
    hipMemsetAsync(d_out, 0, sizeof(float), stream);   // capture-legal
    mst_kernel<<<dim3(2), dim3(NT), 0, stream>>>(d1, d2, out);
}

// Round 2
// 405.946 us; speedup vs baseline: 16.1319x; 16.1319x over previous
//
#include <hip/hip_runtime.h>
#include <stdint.h>

// TopoSignature via parallel Boruvka MST (edge SET is all that matters:
// d symmetric, sum order-independent, MST unique under strict total order
// on keys (weight_bits, lo, hi)).
//
// Per round: scan_k finds each component's min outgoing edge (per-row wave
// reduce + u64 atomicMin into best[comp]); hook_k hooks components along
// their min edge (only 2-cycles possible -> resolve), records edges,
// pointer-jumps, contracts labels. <=12 rounds guaranteed (components at
// least halve). Rounds after completion early-exit on ncomp==1.

#define N       4096
#define NROUNDS 12
#define SCAN_BPM 256                 // scan blocks per matrix
#define ROWS_PER_BLOCK (N / SCAN_BPM) // 16 rows/block, 4 per wave

typedef unsigned long long u64;
typedef uint32_t u32;

struct Ws {
    u64 best[2][N];     // per-component min outgoing edge key: (wbits<<24)|(lo<<12)|hi
    u32 comp[2][N];     // vertex -> component root label
    u32 edges[2][N];    // recorded MST edges, (lo<<12)|hi
    u32 ecnt[2];
    u32 ncomp[2];
};

__device__ __forceinline__ u64 shfl_down_u64(u64 x, int off) {
    u32 lo = (u32)x, hi = (u32)(x >> 32);
    lo = (u32)__shfl_down((int)lo, off, 64);
    hi = (u32)__shfl_down((int)hi, off, 64);
    return ((u64)hi << 32) | lo;
}

__global__ void init_k(Ws* __restrict__ ws) {
    int i = blockIdx.x * blockDim.x + threadIdx.x;
    if (i < N) {
        ws->best[0][i] = ~0ull; ws->best[1][i] = ~0ull;
        ws->comp[0][i] = (u32)i; ws->comp[1][i] = (u32)i;
        if (i < 2) { ws->ecnt[i] = 0u; ws->ncomp[i] = (u32)N; }
    }
}

// Find min outgoing edge per row, atomicMin into best[comp[row]].
__launch_bounds__(256, 2)
__global__ void scan_k(const float* __restrict__ d1, const float* __restrict__ d2,
                       Ws* __restrict__ ws) {
    const int m = blockIdx.x / SCAN_BPM;
    const int b = blockIdx.x % SCAN_BPM;
    if (ws->ncomp[m] <= 1u) return;          // uniform per block
    const float* __restrict__ dm = m ? d2 : d1;

    __shared__ u32 compLDS[N];               // 16 KB
    const int tid = threadIdx.x;
    {
        uint4* dst = (uint4*)compLDS;
        const uint4* src = (const uint4*)ws->comp[m];
        for (int k = tid; k < N / 4; k += 256) dst[k] = src[k];
    }
    __syncthreads();

    const int wave = tid >> 6, lane = tid & 63;
    const uint4* c4 = (const uint4*)compLDS;

    #pragma unroll
    for (int rr = 0; rr < ROWS_PER_BLOCK / 4; ++rr) {
        const int v = b * ROWS_PER_BLOCK + rr * 4 + wave;
        const u32 cv = compLDS[v];
        const float4* row4 = (const float4*)(dm + (size_t)v * N);

        // per-row key: (wbits<<32)|u  (within a fixed row, global order
        // (w,lo,hi) reduces to (w,u) — smaller u wins ties either side of v)
        u64 kmin = ~0ull;
        for (int c = lane; c < N / 4; c += 64) {
            float4 w = row4[c];
            uint4 cu = c4[c];
            u32 u0 = (u32)(4 * c);
            if (cu.x != cv) { u64 k = ((u64)__float_as_uint(w.x) << 32) | (u0 + 0); if (k < kmin) kmin = k; }
            if (cu.y != cv) { u64 k = ((u64)__float_as_uint(w.y) << 32) | (u0 + 1); if (k < kmin) kmin = k; }
            if (cu.z != cv) { u64 k = ((u64)__float_as_uint(w.z) << 32) | (u0 + 2); if (k < kmin) kmin = k; }
            if (cu.w != cv) { u64 k = ((u64)__float_as_uint(w.w) << 32) | (u0 + 3); if (k < kmin) kmin = k; }
        }
        #pragma unroll
        for (int off = 32; off >= 1; off >>= 1) {
            u64 o = shfl_down_u64(kmin, off);
            if (o < kmin) kmin = o;
        }
        if (lane == 0 && kmin != ~0ull) {
            u32 wb = (u32)(kmin >> 32);
            u32 u  = (u32)kmin & 0xFFFu;
            u32 lo = min((u32)v, u), hi = max((u32)v, u);
            u64 g = ((u64)wb << 24) | ((u64)lo << 12) | (u64)hi;
            atomicMin(&ws->best[m][cv], g);
        }
    }
}

// Hook roots along min edges, resolve 2-cycles, record edges, pointer-jump,
// relabel comp, reset best, update ncomp. One block per matrix.
__launch_bounds__(256, 1)
__global__ void hook_k(Ws* __restrict__ ws) {
    const int m = blockIdx.x;
    const int tid = threadIdx.x;
    if (ws->ncomp[m] <= 1u) return;

    u32* __restrict__ gcomp = ws->comp[m];
    u64* __restrict__ best  = ws->best[m];

    __shared__ u32 compL[N];   // old labels (read-only after load)
    __shared__ u32 nxtA[N];    // raw hooks
    __shared__ u32 nxtB[N];    // fixed hooks -> jumped roots
    __shared__ u32 red[4];

    {
        uint4* dst = (uint4*)compL;
        const uint4* src = (const uint4*)gcomp;
        for (int k = tid; k < N / 4; k += 256) dst[k] = src[k];
    }
    __syncthreads();

    bool isroot[16];
    u64  bkey[16];

    // A: each root hooks toward the other endpoint's component
    #pragma unroll
    for (int k = 0; k < 16; ++k) {
        int i = tid + k * 256;
        u32 x = (u32)i;
        bool r = (compL[i] == (u32)i);
        isroot[k] = r;
        u64 g = 0;
        if (r) {
            g = best[i];
            u32 lo = (u32)(g >> 12) & 0xFFFu;
            u32 hi = (u32)g & 0xFFFu;
            u32 cl = compL[lo], ch = compL[hi];
            x = (cl == (u32)i) ? ch : cl;
        }
        bkey[k] = g;
        nxtA[i] = x;
    }
    __syncthreads();

    // B: only 2-cycles possible (strict total order); smaller id becomes root.
    // Mutual pair shares the SAME edge -> recorded once (by the non-root).
    #pragma unroll
    for (int k = 0; k < 16; ++k) {
        int i = tid + k * 256;
        u32 nn = (u32)i;
        if (isroot[k]) {
            u32 o = nxtA[i];
            bool mutual = (nxtA[o] == (u32)i);
            nn = (mutual && ((u32)i < o)) ? (u32)i : o;
            if (nn != (u32)i) {
                u32 pos = atomicAdd(&ws->ecnt[m], 1u);
                if (pos < (u32)N) ws->edges[m][pos] = (u32)(bkey[k] & 0xFFFFFFu);
            }
        }
        nxtB[i] = nn;
    }
    __syncthreads();

    // C: pointer jumping, 12 steps covers depth 4096
    for (int s = 0; s < 12; ++s) {
        #pragma unroll
        for (int k = 0; k < 16; ++k) {
            int i = tid + k * 256;
            nxtB[i] = nxtB[nxtB[i]];
        }
        __syncthreads();
    }

    // D: count surviving roots (among OLD roots)
    u32 cnt = 0;
    #pragma unroll
    for (int k = 0; k < 16; ++k) {
        int i = tid + k * 256;
        if (isroot[k] && nxtB[i] == (u32)i) cnt++;
    }
    #pragma unroll
    for (int off = 32; off >= 1; off >>= 1) cnt += (u32)__shfl_down((int)cnt, off, 64);
    const int lane = tid & 63, wave = tid >> 6;
    if (lane == 0) red[wave] = cnt;
    __syncthreads();

    // E: relabel comp (global), reset best cells of old roots
    #pragma unroll
    for (int k = 0; k < 16; ++k) {
        int i = tid + k * 256;
        gcomp[i] = nxtB[compL[i]];
        if (isroot[k]) best[i] = ~0ull;
    }
    if (tid == 0) ws->ncomp[m] = red[0] + red[1] + red[2] + red[3];
}

__launch_bounds__(256, 1)
__global__ void epi_k(const float* __restrict__ d1, const float* __restrict__ d2,
                      Ws* __restrict__ ws, float* __restrict__ out) {
    const int m = blockIdx.x, tid = threadIdx.x;
    u32 cnt = ws->ecnt[m];
    if (cnt > (u32)N) cnt = (u32)N;
    float acc = 0.f;
    for (u32 i = (u32)tid; i < cnt; i += 256u) {
        u32 pk = ws->edges[m][i];
        u32 lo = (pk >> 12) & 0xFFFu, hi = pk & 0xFFFu;
        size_t off = (size_t)lo * N + hi;
        float df = d1[off] - d2[off];
        acc += df * df;
    }
    #pragma unroll
    for (int off = 32; off >= 1; off >>= 1) acc += __shfl_down(acc, off, 64);
    __shared__ float part[4];
    const int lane = tid & 63, wave = tid >> 6;
    if (lane == 0) part[wave] = acc;
    __syncthreads();
    if (tid == 0) atomicAdd(out, part[0] + part[1] + part[2] + part[3]);
}

extern "C" void kernel_launch(void* const* d_in, const int* in_sizes, int n_in,
                              void* d_out, int out_size, void* d_ws, size_t ws_size,
                              hipStream_t stream) {
    (void)in_sizes; (void)n_in; (void)out_size; (void)ws_size;
    const float* d1 = (const float*)d_in[0];
    const float* d2 = (const float*)d_in[1];
    float* out = (float*)d_out;
    Ws* ws = (Ws*)d_ws;   // needs ~208 KB of scratch

    hipMemsetAsync(d_out, 0, sizeof(float), stream);
    init_k<<<dim3(16), dim3(256), 0, stream>>>(ws);
    for (int r = 0; r < NROUNDS; ++r) {
        scan_k<<<dim3(2 * SCAN_BPM), dim3(256), 0, stream>>>(d1, d2, ws);
        hook_k<<<dim3(2), dim3(256), 0, stream>>>(ws);
    }
    epi_k<<<dim3(2), dim3(256), 0, stream>>>(d1, d2, ws, out);
}